// Round 5
// baseline (442.579 us; speedup 1.0000x reference)
//
#include <hip/hip_runtime.h>
#include <hip/hip_bf16.h>

#define T_TOK 2048
#define HID 2048
#define IMED 768
#define NEXP 16
#define TOPK 8
#define MAXPAIR (T_TOK * TOPK)

using f32x4  = __attribute__((ext_vector_type(4))) float;
using bf16x8 = __attribute__((ext_vector_type(8))) __bf16;

__device__ __forceinline__ f32x4 mfma16(bf16x8 a, bf16x8 b, f32x4 c) {
  return __builtin_amdgcn_mfma_f32_16x16x32_bf16(a, b, c, 0, 0, 0);
}

__device__ __forceinline__ void gload16(const void* g, void* lds) {
  __builtin_amdgcn_global_load_lds((const __attribute__((address_space(1))) unsigned int*)g,
                                   (__attribute__((address_space(3))) unsigned int*)lds,
                                   16, 0, 0);
}

#define BAR() do { asm volatile("s_barrier" ::: "memory"); \
                   __builtin_amdgcn_sched_barrier(0); } while (0)
#define LGKM0() do { asm volatile("s_waitcnt lgkmcnt(0)" ::: "memory"); \
                     __builtin_amdgcn_sched_barrier(0); } while (0)
#define WAITV(N) asm volatile("s_waitcnt vmcnt(" #N ")" ::: "memory")

// ---------- prep: fp32 -> bf16 copy of hidden_states ----------
__global__ void moe_cvt_x(const float* __restrict__ X, __bf16* __restrict__ XB) {
  int i = (blockIdx.x * blockDim.x + threadIdx.x) * 8;
  float4 v0 = *(const float4*)&X[i];
  float4 v1 = *(const float4*)&X[i + 4];
  bf16x8 o;
  o[0] = (__bf16)v0.x; o[1] = (__bf16)v0.y; o[2] = (__bf16)v0.z; o[3] = (__bf16)v0.w;
  o[4] = (__bf16)v1.x; o[5] = (__bf16)v1.y; o[6] = (__bf16)v1.z; o[7] = (__bf16)v1.w;
  *(bf16x8*)&XB[i] = o;
}

// ---------- prep: per-expert transpose [R][C] f32 -> [C][R] bf16, 64x64 tiles ----------
__global__ __launch_bounds__(256) void moe_transpose(const float* __restrict__ in,
                                                     __bf16* __restrict__ out,
                                                     int R, int C) {
  __shared__ __align__(16) float tile[64][68];
  const int e = blockIdx.z;
  const float* ib = in + (size_t)e * R * C;
  __bf16* ob = out + (size_t)e * R * C;
  const int c0 = blockIdx.x * 64, r0 = blockIdx.y * 64;
  const int tid = threadIdx.x;
  const int lr = tid >> 4;
  const int lc = (tid & 15) * 4;
#pragma unroll
  for (int i = 0; i < 4; ++i) {
    int r = lr + i * 16;
    float4 v = *(const float4*)&ib[(size_t)(r0 + r) * C + c0 + lc];
    *(float4*)&tile[r][lc] = v;
  }
  __syncthreads();
  const int oc = tid >> 2;
  const int sr = (tid & 3) * 16;
  bf16x8 o0, o1;
#pragma unroll
  for (int j = 0; j < 8; ++j) o0[j] = (__bf16)tile[sr + j][oc];
#pragma unroll
  for (int j = 0; j < 8; ++j) o1[j] = (__bf16)tile[sr + 8 + j][oc];
  *(bf16x8*)&ob[(size_t)(c0 + oc) * R + r0 + sr] = o0;
  *(bf16x8*)&ob[(size_t)(c0 + oc) * R + r0 + sr + 8] = o1;
}

// ---------- routing ----------
// meta ints: [0..15]=counts  [16..32]=offsets(17)  [33..48]=cursors
__global__ void moe_route_build(const int* __restrict__ idx, const float* __restrict__ wgt,
                                float* __restrict__ combine, int* __restrict__ meta) {
  int t = blockIdx.x * blockDim.x + threadIdx.x;
  if (t >= T_TOK) return;
  float c[NEXP];
#pragma unroll
  for (int e = 0; e < NEXP; ++e) c[e] = 0.f;
  for (int k = 0; k < TOPK; ++k) c[idx[t * TOPK + k]] += wgt[t * TOPK + k];
  for (int e = 0; e < NEXP; ++e) {
    combine[t * NEXP + e] = c[e];
    if (c[e] != 0.f) atomicAdd(&meta[e], 1);
  }
}

__global__ void moe_scan(int* __restrict__ meta) {
  if (threadIdx.x == 0 && blockIdx.x == 0) {
    int s = 0;
    for (int e = 0; e < NEXP; ++e) { meta[16 + e] = s; meta[33 + e] = s; s += meta[e]; }
    meta[32] = s;
  }
}

__global__ void moe_scatter(const float* __restrict__ combine, int* __restrict__ meta,
                            int* __restrict__ route_tok, float* __restrict__ route_w) {
  int t = blockIdx.x * blockDim.x + threadIdx.x;
  if (t >= T_TOK) return;
  for (int e = 0; e < NEXP; ++e) {
    float c = combine[t * NEXP + e];
    if (c != 0.f) {
      int p = atomicAdd(&meta[33 + e], 1);
      route_tok[p] = t;
      route_w[p] = c;
    }
  }
}

// ================= fine-phased K-loop shared shape =================
// BM=128, BN=256 B-rows, BK=64, 8 waves (2Mx4N), wave tile 64x64.
// 3 LDS slots, stage 2 K-tiles ahead, vmcnt(6) at K-tile boundary.
// 4 phases/K-tile: {reads quadrant | stage chunk | BAR | LGKM0 | 8 MFMA | BAR}

// ---------- GEMM1 ----------
__global__ __launch_bounds__(512, 2) void moe_gemm1(
    const __bf16* __restrict__ XB, const __bf16* __restrict__ WguT,
    const int* __restrict__ rtok, const float* __restrict__ rw,
    const int* __restrict__ meta, __bf16* __restrict__ ACT) {
  const int orig = blockIdx.x;                 // 1536 = 8 XCDs x 192
  const int wgid = (orig & 7) * 192 + (orig >> 3);
  const int e   = wgid / 96;
  const int rem = wgid % 96;
  const int ny  = rem >> 4;                    // 0..5
  const int mx  = rem & 15;                    // 0..15

  const int seg0 = meta[16 + e];
  const int cnt  = meta[16 + e + 1] - seg0;
  const int m0 = mx * 128;
  if (m0 >= cnt) return;
  const int n0 = ny * 128;

  __shared__ __align__(16) char As[3 * 16384];
  __shared__ __align__(16) char Bs[3 * 32768];

  const int tid = threadIdx.x;
  const int l = tid & 63;
  const int w = tid >> 6;
  const int wm = w >> 2, wn = w & 3;
  const int swoff = 16 * ((l & 7) ^ (l >> 3));

  const char* baseA[2];
  const char* baseB[4];
#pragma unroll
  for (int q = 0; q < 2; ++q) {
    const int r = (w * 2 + q) * 8 + (l >> 3);
    int grow = m0 + r; if (grow >= cnt) grow = cnt - 1;
    const int tok = rtok[seg0 + grow];
    baseA[q] = (const char*)(XB + (size_t)tok * HID) + swoff;
  }
#pragma unroll
  for (int q = 0; q < 4; ++q) {
    const int r = (w * 4 + q) * 8 + (l >> 3);
    const int s = r & 63;
    const int wr = (s < 32) ? (n0 + (r >> 6) * 32 + s)
                            : (IMED + n0 + (r >> 6) * 32 + (s - 32));
    baseB[q] = (const char*)(WguT + ((size_t)e * (2 * IMED) + wr) * HID) + swoff;
  }

  f32x4 acc[4][4];   // ni 0,1 = gate ; 2,3 = up
  const f32x4 zero = {0.f, 0.f, 0.f, 0.f};
#pragma unroll
  for (int i = 0; i < 4; ++i)
#pragma unroll
    for (int j = 0; j < 4; ++j) acc[i][j] = zero;

  auto stageA = [&](int b, int t) {
    const int k0b = t * 128;
#pragma unroll
    for (int q = 0; q < 2; ++q)
      gload16(baseA[q] + k0b, &As[b * 16384 + (w * 2 + q) * 1024]);
  };
  auto stageB = [&](int b, int t, int h) {
    const int k0b = t * 128;
#pragma unroll
    for (int q = 0; q < 2; ++q)
      gload16(baseB[h * 2 + q] + k0b, &Bs[b * 32768 + (w * 4 + h * 2 + q) * 1024]);
  };

  const int NT = HID / 64;                      // 32
  stageA(0, 0); stageB(0, 0, 0); stageB(0, 0, 1);
  stageA(1, 1); stageB(1, 1, 0); stageB(1, 1, 1);
  WAITV(6); BAR();

  bf16x8 af[4], bfr[4];

  for (int t = 0; t < NT; ++t) {
    const int b = t % 3, bs = (t + 2) % 3;
    const bool st = (t + 2) < NT;
    const char* Ab = &As[b * 16384];
    const char* Bb = &Bs[b * 32768];

    // phase 0: ks=0, A all + B nj0,1 ; stage A(t+2)
    {
      const int colb = (l >> 4) << 4;
#pragma unroll
      for (int mi = 0; mi < 4; ++mi) {
        const int row = wm * 64 + mi * 16 + (l & 15);
        af[mi] = *(const bf16x8*)&Ab[row * 128 + (colb ^ ((row & 7) << 4))];
      }
#pragma unroll
      for (int nj = 0; nj < 2; ++nj) {
        const int row = wn * 64 + nj * 16 + (l & 15);
        bfr[nj] = *(const bf16x8*)&Bb[row * 128 + (colb ^ ((row & 7) << 4))];
      }
      if (st) stageA(bs, t + 2);
      BAR(); LGKM0();
      __builtin_amdgcn_s_setprio(1);
#pragma unroll
      for (int mi = 0; mi < 4; ++mi) {
        acc[mi][0] = mfma16(af[mi], bfr[0], acc[mi][0]);
        acc[mi][1] = mfma16(af[mi], bfr[1], acc[mi][1]);
      }
      __builtin_amdgcn_s_setprio(0);
      BAR();
    }
    // phase 1: ks=0, B nj2,3 ; stage B-h0(t+2)
    {
      const int colb = (l >> 4) << 4;
#pragma unroll
      for (int nj = 2; nj < 4; ++nj) {
        const int row = wn * 64 + nj * 16 + (l & 15);
        bfr[nj] = *(const bf16x8*)&Bb[row * 128 + (colb ^ ((row & 7) << 4))];
      }
      if (st) stageB(bs, t + 2, 0);
      BAR(); LGKM0();
      __builtin_amdgcn_s_setprio(1);
#pragma unroll
      for (int mi = 0; mi < 4; ++mi) {
        acc[mi][2] = mfma16(af[mi], bfr[2], acc[mi][2]);
        acc[mi][3] = mfma16(af[mi], bfr[3], acc[mi][3]);
      }
      __builtin_amdgcn_s_setprio(0);
      BAR();
    }
    // phase 2: ks=1, A all + B nj0,1 ; stage B-h1(t+2)
    {
      const int colb = 64 + ((l >> 4) << 4);
#pragma unroll
      for (int mi = 0; mi < 4; ++mi) {
        const int row = wm * 64 + mi * 16 + (l & 15);
        af[mi] = *(const bf16x8*)&Ab[row * 128 + (colb ^ ((row & 7) << 4))];
      }
#pragma unroll
      for (int nj = 0; nj < 2; ++nj) {
        const int row = wn * 64 + nj * 16 + (l & 15);
        bfr[nj] = *(const bf16x8*)&Bb[row * 128 + (colb ^ ((row & 7) << 4))];
      }
      if (st) stageB(bs, t + 2, 1);
      BAR(); LGKM0();
      __builtin_amdgcn_s_setprio(1);
#pragma unroll
      for (int mi = 0; mi < 4; ++mi) {
        acc[mi][0] = mfma16(af[mi], bfr[0], acc[mi][0]);
        acc[mi][1] = mfma16(af[mi], bfr[1], acc[mi][1]);
      }
      __builtin_amdgcn_s_setprio(0);
      BAR();
    }
    // phase 3: ks=1, B nj2,3 ; K-tile boundary wait
    {
      const int colb = 64 + ((l >> 4) << 4);
#pragma unroll
      for (int nj = 2; nj < 4; ++nj) {
        const int row = wn * 64 + nj * 16 + (l & 15);
        bfr[nj] = *(const bf16x8*)&Bb[row * 128 + (colb ^ ((row & 7) << 4))];
      }
      if (t < NT - 2) { WAITV(6); } else { WAITV(0); }
      BAR(); LGKM0();
      __builtin_amdgcn_s_setprio(1);
#pragma unroll
      for (int mi = 0; mi < 4; ++mi) {
        acc[mi][2] = mfma16(af[mi], bfr[2], acc[mi][2]);
        acc[mi][3] = mfma16(af[mi], bfr[3], acc[mi][3]);
      }
      __builtin_amdgcn_s_setprio(0);
      BAR();
    }
  }

  const int cbase = n0 + wn * 32;
#pragma unroll
  for (int mi = 0; mi < 4; ++mi) {
    const int rb = wm * 64 + mi * 16 + ((l >> 4) << 2);
#pragma unroll
    for (int r = 0; r < 4; ++r) {
      const int row = m0 + rb + r;
      if (row < cnt) {
        const float wgt = rw[seg0 + row];
#pragma unroll
        for (int ni = 0; ni < 2; ++ni) {
          const float g = acc[mi][ni][r];
          const float u = acc[mi][ni + 2][r];
          const float s = g / (1.f + __expf(-g));
          ACT[(size_t)(seg0 + row) * IMED + cbase + ni * 16 + (l & 15)] = (__bf16)(s * u * wgt);
        }
      }
    }
  }
}

// ---------- GEMM2 ----------
__global__ __launch_bounds__(512, 2) void moe_gemm2(
    const __bf16* __restrict__ ACT, const __bf16* __restrict__ WdT,
    const int* __restrict__ rtok, const int* __restrict__ meta,
    float* __restrict__ out) {
  const int orig = blockIdx.x;                 // 2048 = 8 x 256
  const int wgid = (orig & 7) * 256 + (orig >> 3);
  const int e   = wgid >> 7;
  const int rem = wgid & 127;
  const int ny  = rem >> 4;                    // 0..7
  const int mx  = rem & 15;

  const int seg0 = meta[16 + e];
  const int cnt  = meta[16 + e + 1] - seg0;
  const int m0 = mx * 128;
  if (m0 >= cnt) return;
  const int n0 = ny * 256;

  __shared__ __align__(16) char As[3 * 16384];
  __shared__ __align__(16) char Bs[3 * 32768];

  const int tid = threadIdx.x;
  const int l = tid & 63;
  const int w = tid >> 6;
  const int wm = w >> 2, wn = w & 3;
  const int swoff = 16 * ((l & 7) ^ (l >> 3));

  const char* baseA[2];
  const char* baseB[4];
#pragma unroll
  for (int q = 0; q < 2; ++q) {
    const int r = (w * 2 + q) * 8 + (l >> 3);
    int grow = m0 + r; if (grow >= cnt) grow = cnt - 1;
    baseA[q] = (const char*)(ACT + (size_t)(seg0 + grow) * IMED) + swoff;
  }
#pragma unroll
  for (int q = 0; q < 4; ++q) {
    const int r = (w * 4 + q) * 8 + (l >> 3);
    baseB[q] = (const char*)(WdT + ((size_t)e * HID + n0 + r) * IMED) + swoff;
  }

  f32x4 acc[4][4];
  const f32x4 zero = {0.f, 0.f, 0.f, 0.f};
#pragma unroll
  for (int i = 0; i < 4; ++i)
#pragma unroll
    for (int j = 0; j < 4; ++j) acc[i][j] = zero;

  auto stageA = [&](int b, int t) {
    const int k0b = t * 128;
#pragma unroll
    for (int q = 0; q < 2; ++q)
      gload16(baseA[q] + k0b, &As[b * 16384 + (w * 2 + q) * 1024]);
  };
  auto stageB = [&](int b, int t, int h) {
    const int k0b = t * 128;
#pragma unroll
    for (int q = 0; q < 2; ++q)
      gload16(baseB[h * 2 + q] + k0b, &Bs[b * 32768 + (w * 4 + h * 2 + q) * 1024]);
  };

  const int NT = IMED / 64;                     // 12
  stageA(0, 0); stageB(0, 0, 0); stageB(0, 0, 1);
  stageA(1, 1); stageB(1, 1, 0); stageB(1, 1, 1);
  WAITV(6); BAR();

  bf16x8 af[4], bfr[4];

  for (int t = 0; t < NT; ++t) {
    const int b = t % 3, bs = (t + 2) % 3;
    const bool st = (t + 2) < NT;
    const char* Ab = &As[b * 16384];
    const char* Bb = &Bs[b * 32768];

    {
      const int colb = (l >> 4) << 4;
#pragma unroll
      for (int mi = 0; mi < 4; ++mi) {
        const int row = wm * 64 + mi * 16 + (l & 15);
        af[mi] = *(const bf16x8*)&Ab[row * 128 + (colb ^ ((row & 7) << 4))];
      }
#pragma unroll
      for (int nj = 0; nj < 2; ++nj) {
        const int row = wn * 64 + nj * 16 + (l & 15);
        bfr[nj] = *(const bf16x8*)&Bb[row * 128 + (colb ^ ((row & 7) << 4))];
      }
      if (st) stageA(bs, t + 2);
      BAR(); LGKM0();
      __builtin_amdgcn_s_setprio(1);
#pragma unroll
      for (int mi = 0; mi < 4; ++mi) {
        acc[mi][0] = mfma16(af[mi], bfr[0], acc[mi][0]);
        acc[mi][1] = mfma16(af[mi], bfr[1], acc[mi][1]);
      }
      __builtin_amdgcn_s_setprio(0);
      BAR();
    }
    {
      const int colb = (l >> 4) << 4;
#pragma unroll
      for (int nj = 2; nj < 4; ++nj) {
        const int row = wn * 64 + nj * 16 + (l & 15);
        bfr[nj] = *(const bf16x8*)&Bb[row * 128 + (colb ^ ((row & 7) << 4))];
      }
      if (st) stageB(bs, t + 2, 0);
      BAR(); LGKM0();
      __builtin_amdgcn_s_setprio(1);
#pragma unroll
      for (int mi = 0; mi < 4; ++mi) {
        acc[mi][2] = mfma16(af[mi], bfr[2], acc[mi][2]);
        acc[mi][3] = mfma16(af[mi], bfr[3], acc[mi][3]);
      }
      __builtin_amdgcn_s_setprio(0);
      BAR();
    }
    {
      const int colb = 64 + ((l >> 4) << 4);
#pragma unroll
      for (int mi = 0; mi < 4; ++mi) {
        const int row = wm * 64 + mi * 16 + (l & 15);
        af[mi] = *(const bf16x8*)&Ab[row * 128 + (colb ^ ((row & 7) << 4))];
      }
#pragma unroll
      for (int nj = 0; nj < 2; ++nj) {
        const int row = wn * 64 + nj * 16 + (l & 15);
        bfr[nj] = *(const bf16x8*)&Bb[row * 128 + (colb ^ ((row & 7) << 4))];
      }
      if (st) stageB(bs, t + 2, 1);
      BAR(); LGKM0();
      __builtin_amdgcn_s_setprio(1);
#pragma unroll
      for (int mi = 0; mi < 4; ++mi) {
        acc[mi][0] = mfma16(af[mi], bfr[0], acc[mi][0]);
        acc[mi][1] = mfma16(af[mi], bfr[1], acc[mi][1]);
      }
      __builtin_amdgcn_s_setprio(0);
      BAR();
    }
    {
      const int colb = 64 + ((l >> 4) << 4);
#pragma unroll
      for (int nj = 2; nj < 4; ++nj) {
        const int row = wn * 64 + nj * 16 + (l & 15);
        bfr[nj] = *(const bf16x8*)&Bb[row * 128 + (colb ^ ((row & 7) << 4))];
      }
      if (t < NT - 2) { WAITV(6); } else { WAITV(0); }
      BAR(); LGKM0();
      __builtin_amdgcn_s_setprio(1);
#pragma unroll
      for (int mi = 0; mi < 4; ++mi) {
        acc[mi][2] = mfma16(af[mi], bfr[2], acc[mi][2]);
        acc[mi][3] = mfma16(af[mi], bfr[3], acc[mi][3]);
      }
      __builtin_amdgcn_s_setprio(0);
      BAR();
    }
  }

#pragma unroll
  for (int mi = 0; mi < 4; ++mi) {
    const int rb = wm * 64 + mi * 16 + ((l >> 4) << 2);
#pragma unroll
    for (int r = 0; r < 4; ++r) {
      const int row = m0 + rb + r;
      if (row < cnt) {
        const int tok = rtok[seg0 + row];
#pragma unroll
        for (int ni = 0; ni < 4; ++ni)
          atomicAdd(&out[(size_t)tok * HID + n0 + wn * 64 + ni * 16 + (l & 15)],
                    acc[mi][ni][r]);
      }
    }
  }
}

extern "C" void kernel_launch(void* const* d_in, const int* in_sizes, int n_in,
                              void* d_out, int out_size, void* d_ws, size_t ws_size,
                              hipStream_t stream) {
  const float* X   = (const float*)d_in[0];
  const float* GUP = (const float*)d_in[1];
  const float* DP  = (const float*)d_in[2];
  const int*   IDX = (const int*)d_in[3];
  const float* W   = (const float*)d_in[4];
  float* out = (float*)d_out;

  size_t off = 0;
  auto alloc = [&](size_t bytes) -> void* {
    void* p = (char*)d_ws + off;
    off = (off + bytes + 255) & ~(size_t)255;
    return p;
  };
  __bf16* XB      = (__bf16*)alloc((size_t)T_TOK * HID * 2);
  __bf16* WguT    = (__bf16*)alloc((size_t)NEXP * 2 * IMED * HID * 2);
  __bf16* WdT     = (__bf16*)alloc((size_t)NEXP * HID * IMED * 2);
  __bf16* ACT     = (__bf16*)alloc((size_t)(MAXPAIR + 128) * IMED * 2);
  float*  combine = (float*)alloc((size_t)T_TOK * NEXP * 4);
  int*    meta    = (int*)alloc(64 * 4);
  int*    rtok    = (int*)alloc((size_t)MAXPAIR * 4);
  float*  rw      = (float*)alloc((size_t)MAXPAIR * 4);
  if (off > ws_size) return;

  hipMemsetAsync(meta, 0, 256, stream);
  moe_cvt_x<<<T_TOK * HID / (256 * 8), 256, 0, stream>>>(X, XB);
  moe_transpose<<<dim3((2 * IMED) / 64, HID / 64, NEXP), 256, 0, stream>>>(GUP, WguT, HID, 2 * IMED);
  moe_transpose<<<dim3(HID / 64, IMED / 64, NEXP), 256, 0, stream>>>(DP, WdT, IMED, HID);
  moe_route_build<<<T_TOK / 256, 256, 0, stream>>>(IDX, W, combine, meta);
  moe_scan<<<1, 64, 0, stream>>>(meta);
  moe_scatter<<<T_TOK / 256, 256, 0, stream>>>(combine, meta, rtok, rw);
  hipMemsetAsync(d_out, 0, (size_t)T_TOK * HID * 4, stream);
  moe_gemm1<<<1536, 512, 0, stream>>>(XB, WguT, rtok, rw, meta, ACT);
  moe_gemm2<<<2048, 512, 0, stream>>>(ACT, WdT, rtok, meta, out);
}

// Round 6
// 340.747 us; speedup vs baseline: 1.2988x; 1.2988x over previous
//
#include <hip/hip_runtime.h>
#include <hip/hip_bf16.h>

#define T_TOK 2048
#define HID 2048
#define IMED 768
#define NEXP 16
#define TOPK 8
#define MAXPAIR (T_TOK * TOPK)

using f32x4  = __attribute__((ext_vector_type(4))) float;
using bf16x8 = __attribute__((ext_vector_type(8))) __bf16;

__device__ __forceinline__ f32x4 mfma16(bf16x8 a, bf16x8 b, f32x4 c) {
  return __builtin_amdgcn_mfma_f32_16x16x32_bf16(a, b, c, 0, 0, 0);
}

__device__ __forceinline__ void gload16(const void* g, void* lds) {
  __builtin_amdgcn_global_load_lds((const __attribute__((address_space(1))) unsigned int*)g,
                                   (__attribute__((address_space(3))) unsigned int*)lds,
                                   16, 0, 0);
}

// ---------- prep: fp32 -> bf16 copy of hidden_states ----------
__global__ void moe_cvt_x(const float* __restrict__ X, __bf16* __restrict__ XB) {
  int i = (blockIdx.x * blockDim.x + threadIdx.x) * 8;
  float4 v0 = *(const float4*)&X[i];
  float4 v1 = *(const float4*)&X[i + 4];
  bf16x8 o;
  o[0] = (__bf16)v0.x; o[1] = (__bf16)v0.y; o[2] = (__bf16)v0.z; o[3] = (__bf16)v0.w;
  o[4] = (__bf16)v1.x; o[5] = (__bf16)v1.y; o[6] = (__bf16)v1.z; o[7] = (__bf16)v1.w;
  *(bf16x8*)&XB[i] = o;
}

// ---------- prep: per-expert transpose [R][C] f32 -> [C][R] bf16, 64x64 tiles ----------
__global__ __launch_bounds__(256) void moe_transpose(const float* __restrict__ in,
                                                     __bf16* __restrict__ out,
                                                     int R, int C) {
  __shared__ __align__(16) float tile[64][68];
  const int e = blockIdx.z;
  const float* ib = in + (size_t)e * R * C;
  __bf16* ob = out + (size_t)e * R * C;
  const int c0 = blockIdx.x * 64, r0 = blockIdx.y * 64;
  const int tid = threadIdx.x;
  const int lr = tid >> 4;
  const int lc = (tid & 15) * 4;
#pragma unroll
  for (int i = 0; i < 4; ++i) {
    int r = lr + i * 16;
    float4 v = *(const float4*)&ib[(size_t)(r0 + r) * C + c0 + lc];
    *(float4*)&tile[r][lc] = v;
  }
  __syncthreads();
  const int oc = tid >> 2;
  const int sr = (tid & 3) * 16;
  bf16x8 o0, o1;
#pragma unroll
  for (int j = 0; j < 8; ++j) o0[j] = (__bf16)tile[sr + j][oc];
#pragma unroll
  for (int j = 0; j < 8; ++j) o1[j] = (__bf16)tile[sr + 8 + j][oc];
  *(bf16x8*)&ob[(size_t)(c0 + oc) * R + r0 + sr] = o0;
  *(bf16x8*)&ob[(size_t)(c0 + oc) * R + r0 + sr + 8] = o1;
}

// ---------- routing ----------
// meta ints: [0..15]=counts  [16..32]=offsets(17)  [33..48]=cursors
__global__ void moe_route_build(const int* __restrict__ idx, const float* __restrict__ wgt,
                                float* __restrict__ combine, int* __restrict__ meta) {
  int t = blockIdx.x * blockDim.x + threadIdx.x;
  if (t >= T_TOK) return;
  float c[NEXP];
#pragma unroll
  for (int e = 0; e < NEXP; ++e) c[e] = 0.f;
  for (int k = 0; k < TOPK; ++k) c[idx[t * TOPK + k]] += wgt[t * TOPK + k];
  for (int e = 0; e < NEXP; ++e) {
    combine[t * NEXP + e] = c[e];
    if (c[e] != 0.f) atomicAdd(&meta[e], 1);
  }
}

__global__ void moe_scan(int* __restrict__ meta) {
  if (threadIdx.x == 0 && blockIdx.x == 0) {
    int s = 0;
    for (int e = 0; e < NEXP; ++e) { meta[16 + e] = s; meta[33 + e] = s; s += meta[e]; }
    meta[32] = s;
  }
}

// also builds per-token inverse map: ptok[t][0..pcnt-1] = pair index
__global__ void moe_scatter(const float* __restrict__ combine, int* __restrict__ meta,
                            int* __restrict__ route_tok, float* __restrict__ route_w,
                            int* __restrict__ ptok, int* __restrict__ pcnt) {
  int t = blockIdx.x * blockDim.x + threadIdx.x;
  if (t >= T_TOK) return;
  int slot = 0;
  for (int e = 0; e < NEXP; ++e) {
    float c = combine[t * NEXP + e];
    if (c != 0.f) {
      int p = atomicAdd(&meta[33 + e], 1);
      route_tok[p] = t;
      route_w[p] = c;
      ptok[t * TOPK + slot] = p;
      ++slot;
    }
  }
  pcnt[t] = slot;
}

// ---------- GEMM1: 128 pairs x (64 gate + 64 up cols), K=2048, 2-phase dbuf ----------
__global__ __launch_bounds__(256) void moe_gemm1(
    const __bf16* __restrict__ XB, const __bf16* __restrict__ WguT,
    const int* __restrict__ rtok, const float* __restrict__ rw,
    const int* __restrict__ meta, __bf16* __restrict__ ACT) {
  // XCD-bijective remap: 3072 WGs = 8 XCDs x 384.
  const int orig = blockIdx.x;
  const int wgid = (orig & 7) * 384 + (orig >> 3);
  const int mx = wgid & 15;
  const int ny = (wgid >> 4) % 12;
  const int e  = wgid / 192;

  const int seg0 = meta[16 + e];
  const int cnt  = meta[16 + e + 1] - seg0;
  const int m0 = mx * 128;
  if (m0 >= cnt) return;
  const int n0 = ny * 64;

  __shared__ char As[2][16384];
  __shared__ char Bs[2][16384];

  const int tid = threadIdx.x;
  const int l = tid & 63;
  const int w = tid >> 6;
  const int wm = w >> 1, wn = w & 1;
  const int swoff = 16 * ((l & 7) ^ (l >> 3));

  const char* baseA[4];
  const char* baseB[4];
#pragma unroll
  for (int q = 0; q < 4; ++q) {
    const int r = (w * 4 + q) * 8 + (l >> 3);
    int grow = m0 + r; if (grow >= cnt) grow = cnt - 1;
    const int tok = rtok[seg0 + grow];
    baseA[q] = (const char*)(XB + (size_t)tok * HID) + swoff;
    const int sec = r >> 6, s = r & 63;
    const int wrow = (s < 32) ? (n0 + sec * 32 + s) : (IMED + n0 + sec * 32 + (s - 32));
    baseB[q] = (const char*)(WguT + ((size_t)e * (2 * IMED) + wrow) * HID) + swoff;
  }

  f32x4 acc[4][4];   // ni 0,1 = gate ; 2,3 = up
  const f32x4 zero = {0.f, 0.f, 0.f, 0.f};
#pragma unroll
  for (int i = 0; i < 4; ++i)
#pragma unroll
    for (int j = 0; j < 4; ++j) acc[i][j] = zero;

  auto STAGE = [&](int buf, int k0b) {
#pragma unroll
    for (int q = 0; q < 4; ++q) {
      gload16(baseA[q] + k0b, &As[buf][(w * 4 + q) * 1024]);
      gload16(baseB[q] + k0b, &Bs[buf][(w * 4 + q) * 1024]);
    }
  };
  auto COMPUTE = [&](int buf) {
#pragma unroll
    for (int ks = 0; ks < 2; ++ks) {
      const int colb = ks * 64 + (l >> 4) * 16;
      bf16x8 af[4], bf[4];
#pragma unroll
      for (int mi = 0; mi < 4; ++mi) {
        const int row = wm * 64 + mi * 16 + (l & 15);
        af[mi] = *(const bf16x8*)&As[buf][row * 128 + (colb ^ ((row & 7) << 4))];
      }
#pragma unroll
      for (int ni = 0; ni < 4; ++ni) {
        const int row = wn * 64 + ni * 16 + (l & 15);
        bf[ni] = *(const bf16x8*)&Bs[buf][row * 128 + (colb ^ ((row & 7) << 4))];
      }
#pragma unroll
      for (int mi = 0; mi < 4; ++mi)
#pragma unroll
        for (int ni = 0; ni < 4; ++ni)
          acc[mi][ni] = mfma16(af[mi], bf[ni], acc[mi][ni]);
    }
  };

  STAGE(0, 0);
  __syncthreads();
  int cur = 0;
  for (int t = 1; t < HID / 64; ++t) {
    STAGE(cur ^ 1, t * 128);
    COMPUTE(cur);
    __syncthreads();
    cur ^= 1;
  }
  COMPUTE(cur);

  const int cbase = n0 + wn * 32;
#pragma unroll
  for (int mi = 0; mi < 4; ++mi) {
    const int rb = wm * 64 + mi * 16 + ((l >> 4) << 2);
#pragma unroll
    for (int r = 0; r < 4; ++r) {
      const int row = m0 + rb + r;
      if (row < cnt) {
        const float wgt = rw[seg0 + row];
#pragma unroll
        for (int ni = 0; ni < 2; ++ni) {
          const float g = acc[mi][ni][r];
          const float u = acc[mi][ni + 2][r];
          const float s = g / (1.f + __expf(-g));
          ACT[(size_t)(seg0 + row) * IMED + cbase + ni * 16 + (l & 15)] = (__bf16)(s * u * wgt);
        }
      }
    }
  }
}

// ---------- GEMM2: 128 pairs x 128 H-cols, K=768, 2-phase dbuf, bf16 store ----------
__global__ __launch_bounds__(256) void moe_gemm2(
    const __bf16* __restrict__ ACT, const __bf16* __restrict__ WdT,
    const int* __restrict__ meta, __bf16* __restrict__ ACT2) {
  const int orig = blockIdx.x;               // 4096 WGs = 8 x 512
  const int wgid = (orig & 7) * 512 + (orig >> 3);
  const int mx = wgid & 15;
  const int ny = (wgid >> 4) & 15;
  const int e  = wgid >> 8;

  const int seg0 = meta[16 + e];
  const int cnt  = meta[16 + e + 1] - seg0;
  const int m0 = mx * 128;
  if (m0 >= cnt) return;
  const int n0 = ny * 128;

  __shared__ char As[2][16384];
  __shared__ char Bs[2][16384];

  const int tid = threadIdx.x;
  const int l = tid & 63;
  const int w = tid >> 6;
  const int wm = w >> 1, wn = w & 1;
  const int swoff = 16 * ((l & 7) ^ (l >> 3));

  const char* baseA[4];
  const char* baseB[4];
#pragma unroll
  for (int q = 0; q < 4; ++q) {
    const int r = (w * 4 + q) * 8 + (l >> 3);
    int grow = m0 + r; if (grow >= cnt) grow = cnt - 1;
    baseA[q] = (const char*)(ACT + (size_t)(seg0 + grow) * IMED) + swoff;
    baseB[q] = (const char*)(WdT + ((size_t)e * HID + n0 + r) * IMED) + swoff;
  }

  f32x4 acc[4][4];
  const f32x4 zero = {0.f, 0.f, 0.f, 0.f};
#pragma unroll
  for (int i = 0; i < 4; ++i)
#pragma unroll
    for (int j = 0; j < 4; ++j) acc[i][j] = zero;

  auto STAGE = [&](int buf, int k0b) {
#pragma unroll
    for (int q = 0; q < 4; ++q) {
      gload16(baseA[q] + k0b, &As[buf][(w * 4 + q) * 1024]);
      gload16(baseB[q] + k0b, &Bs[buf][(w * 4 + q) * 1024]);
    }
  };
  auto COMPUTE = [&](int buf) {
#pragma unroll
    for (int ks = 0; ks < 2; ++ks) {
      const int colb = ks * 64 + (l >> 4) * 16;
      bf16x8 af[4], bf[4];
#pragma unroll
      for (int mi = 0; mi < 4; ++mi) {
        const int row = wm * 64 + mi * 16 + (l & 15);
        af[mi] = *(const bf16x8*)&As[buf][row * 128 + (colb ^ ((row & 7) << 4))];
      }
#pragma unroll
      for (int ni = 0; ni < 4; ++ni) {
        const int row = wn * 64 + ni * 16 + (l & 15);
        bf[ni] = *(const bf16x8*)&Bs[buf][row * 128 + (colb ^ ((row & 7) << 4))];
      }
#pragma unroll
      for (int mi = 0; mi < 4; ++mi)
#pragma unroll
        for (int ni = 0; ni < 4; ++ni)
          acc[mi][ni] = mfma16(af[mi], bf[ni], acc[mi][ni]);
    }
  };

  STAGE(0, 0);
  __syncthreads();
  int cur = 0;
  for (int t = 1; t < IMED / 64; ++t) {
    STAGE(cur ^ 1, t * 128);
    COMPUTE(cur);
    __syncthreads();
    cur ^= 1;
  }
  COMPUTE(cur);

#pragma unroll
  for (int mi = 0; mi < 4; ++mi) {
    const int rb = wm * 64 + mi * 16 + ((l >> 4) << 2);
#pragma unroll
    for (int r = 0; r < 4; ++r) {
      const int row = m0 + rb + r;
      if (row < cnt) {
#pragma unroll
        for (int ni = 0; ni < 4; ++ni)
          ACT2[(size_t)(seg0 + row) * HID + n0 + wn * 64 + ni * 16 + (l & 15)] =
              (__bf16)acc[mi][ni][r];
      }
    }
  }
}

// ---------- combine: out[t][h] = sum_k ACT2[ptok[t][k]][h] ----------
__global__ __launch_bounds__(256) void moe_combine(const __bf16* __restrict__ ACT2,
                                                   const int* __restrict__ ptok,
                                                   const int* __restrict__ pcnt,
                                                   float* __restrict__ out) {
  const int t = blockIdx.x;
  const int h = threadIdx.x * 8;
  const int n = pcnt[t];
  float a[8];
#pragma unroll
  for (int j = 0; j < 8; ++j) a[j] = 0.f;
  for (int k = 0; k < n; ++k) {
    const int p = ptok[t * TOPK + k];
    bf16x8 v = *(const bf16x8*)&ACT2[(size_t)p * HID + h];
#pragma unroll
    for (int j = 0; j < 8; ++j) a[j] += (float)v[j];
  }
  float4 o0 = {a[0], a[1], a[2], a[3]};
  float4 o1 = {a[4], a[5], a[6], a[7]};
  *(float4*)&out[(size_t)t * HID + h] = o0;
  *(float4*)&out[(size_t)t * HID + h + 4] = o1;
}

extern "C" void kernel_launch(void* const* d_in, const int* in_sizes, int n_in,
                              void* d_out, int out_size, void* d_ws, size_t ws_size,
                              hipStream_t stream) {
  const float* X   = (const float*)d_in[0];
  const float* GUP = (const float*)d_in[1];
  const float* DP  = (const float*)d_in[2];
  const int*   IDX = (const int*)d_in[3];
  const float* W   = (const float*)d_in[4];
  float* out = (float*)d_out;

  size_t off = 0;
  auto alloc = [&](size_t bytes) -> void* {
    void* p = (char*)d_ws + off;
    off = (off + bytes + 255) & ~(size_t)255;
    return p;
  };
  __bf16* XB      = (__bf16*)alloc((size_t)T_TOK * HID * 2);
  __bf16* WguT    = (__bf16*)alloc((size_t)NEXP * 2 * IMED * HID * 2);
  __bf16* WdT     = (__bf16*)alloc((size_t)NEXP * HID * IMED * 2);
  __bf16* ACT     = (__bf16*)alloc((size_t)(MAXPAIR + 128) * IMED * 2);
  float*  combine = (float*)alloc((size_t)T_TOK * NEXP * 4);
  int*    meta    = (int*)alloc(64 * 4);
  int*    rtok    = (int*)alloc((size_t)MAXPAIR * 4);
  float*  rw      = (float*)alloc((size_t)MAXPAIR * 4);
  int*    ptok    = (int*)alloc((size_t)T_TOK * TOPK * 4);
  int*    pcnt    = (int*)alloc((size_t)T_TOK * 4);
  if (off > ws_size) return;

  // ACT2 aliases WguT: GEMM1 (last reader of WguT) completes before GEMM2
  // (first writer of ACT2) on the same stream. 67.1 MB <= 100.7 MB region.
  __bf16* ACT2 = WguT;

  hipMemsetAsync(meta, 0, 256, stream);
  moe_cvt_x<<<T_TOK * HID / (256 * 8), 256, 0, stream>>>(X, XB);
  moe_transpose<<<dim3((2 * IMED) / 64, HID / 64, NEXP), 256, 0, stream>>>(GUP, WguT, HID, 2 * IMED);
  moe_transpose<<<dim3(HID / 64, IMED / 64, NEXP), 256, 0, stream>>>(DP, WdT, IMED, HID);
  moe_route_build<<<T_TOK / 256, 256, 0, stream>>>(IDX, W, combine, meta);
  moe_scan<<<1, 64, 0, stream>>>(meta);
  moe_scatter<<<T_TOK / 256, 256, 0, stream>>>(combine, meta, rtok, rw, ptok, pcnt);
  moe_gemm1<<<3072, 256, 0, stream>>>(XB, WguT, rtok, rw, meta, ACT);
  moe_gemm2<<<4096, 256, 0, stream>>>(ACT, WdT, meta, ACT2);
  moe_combine<<<T_TOK, 256, 0, stream>>>(ACT2, ptok, pcnt, out);
}

// Round 7
// 325.929 us; speedup vs baseline: 1.3579x; 1.0455x over previous
//
#include <hip/hip_runtime.h>
#include <hip/hip_bf16.h>

#define T_TOK 2048
#define HID 2048
#define IMED 768
#define NEXP 16
#define TOPK 8
#define MAXPAIR (T_TOK * TOPK)

using f32x4  = __attribute__((ext_vector_type(4))) float;
using bf16x8 = __attribute__((ext_vector_type(8))) __bf16;

__device__ __forceinline__ f32x4 mfma16(bf16x8 a, bf16x8 b, f32x4 c) {
  return __builtin_amdgcn_mfma_f32_16x16x32_bf16(a, b, c, 0, 0, 0);
}

__device__ __forceinline__ void gload16(const void* g, void* lds) {
  __builtin_amdgcn_global_load_lds((const __attribute__((address_space(1))) unsigned int*)g,
                                   (__attribute__((address_space(3))) unsigned int*)lds,
                                   16, 0, 0);
}

// ---------- prep: fp32 -> bf16 copy of hidden_states ----------
__global__ void moe_cvt_x(const float* __restrict__ X, __bf16* __restrict__ XB) {
  int i = (blockIdx.x * blockDim.x + threadIdx.x) * 8;
  float4 v0 = *(const float4*)&X[i];
  float4 v1 = *(const float4*)&X[i + 4];
  bf16x8 o;
  o[0] = (__bf16)v0.x; o[1] = (__bf16)v0.y; o[2] = (__bf16)v0.z; o[3] = (__bf16)v0.w;
  o[4] = (__bf16)v1.x; o[5] = (__bf16)v1.y; o[6] = (__bf16)v1.z; o[7] = (__bf16)v1.w;
  *(bf16x8*)&XB[i] = o;
}

// ---------- prep: per-expert transpose [R][C] f32 -> [C][R] bf16, 64x64 tiles ----------
__global__ __launch_bounds__(256) void moe_transpose(const float* __restrict__ in,
                                                     __bf16* __restrict__ out,
                                                     int R, int C) {
  __shared__ __align__(16) float tile[64][68];
  const int e = blockIdx.z;
  const float* ib = in + (size_t)e * R * C;
  __bf16* ob = out + (size_t)e * R * C;
  const int c0 = blockIdx.x * 64, r0 = blockIdx.y * 64;
  const int tid = threadIdx.x;
  const int lr = tid >> 4;
  const int lc = (tid & 15) * 4;
#pragma unroll
  for (int i = 0; i < 4; ++i) {
    int r = lr + i * 16;
    float4 v = *(const float4*)&ib[(size_t)(r0 + r) * C + c0 + lc];
    *(float4*)&tile[r][lc] = v;
  }
  __syncthreads();
  const int oc = tid >> 2;
  const int sr = (tid & 3) * 16;
  bf16x8 o0, o1;
#pragma unroll
  for (int j = 0; j < 8; ++j) o0[j] = (__bf16)tile[sr + j][oc];
#pragma unroll
  for (int j = 0; j < 8; ++j) o1[j] = (__bf16)tile[sr + 8 + j][oc];
  *(bf16x8*)&ob[(size_t)(c0 + oc) * R + r0 + sr] = o0;
  *(bf16x8*)&ob[(size_t)(c0 + oc) * R + r0 + sr + 8] = o1;
}

// ---------- routing ----------
// meta ints: [0..15]=counts  [16..32]=offsets(17)  [33..48]=cursors
__global__ void moe_route_build(const int* __restrict__ idx, const float* __restrict__ wgt,
                                float* __restrict__ combine, int* __restrict__ meta) {
  int t = blockIdx.x * blockDim.x + threadIdx.x;
  if (t >= T_TOK) return;
  float c[NEXP];
#pragma unroll
  for (int e = 0; e < NEXP; ++e) c[e] = 0.f;
  for (int k = 0; k < TOPK; ++k) c[idx[t * TOPK + k]] += wgt[t * TOPK + k];
  for (int e = 0; e < NEXP; ++e) {
    combine[t * NEXP + e] = c[e];
    if (c[e] != 0.f) atomicAdd(&meta[e], 1);
  }
}

__global__ void moe_scan(int* __restrict__ meta) {
  if (threadIdx.x == 0 && blockIdx.x == 0) {
    int s = 0;
    for (int e = 0; e < NEXP; ++e) { meta[16 + e] = s; meta[33 + e] = s; s += meta[e]; }
    meta[32] = s;
  }
}

// also builds per-token inverse map: ptok[t][0..pcnt-1] = pair index
__global__ void moe_scatter(const float* __restrict__ combine, int* __restrict__ meta,
                            int* __restrict__ route_tok, float* __restrict__ route_w,
                            int* __restrict__ ptok, int* __restrict__ pcnt) {
  int t = blockIdx.x * blockDim.x + threadIdx.x;
  if (t >= T_TOK) return;
  int slot = 0;
  for (int e = 0; e < NEXP; ++e) {
    float c = combine[t * NEXP + e];
    if (c != 0.f) {
      int p = atomicAdd(&meta[33 + e], 1);
      route_tok[p] = t;
      route_w[p] = c;
      ptok[t * TOPK + slot] = p;
      ++slot;
    }
  }
  pcnt[t] = slot;
}

// ---------- GEMM1: 128 pairs x (64 gate + 64 up cols), K=2048 ----------
// m97 structure: single 32KB LDS buffer, stage->sync->compute->sync, ~5 WG/CU.
__global__ __launch_bounds__(256) void moe_gemm1(
    const __bf16* __restrict__ XB, const __bf16* __restrict__ WguT,
    const int* __restrict__ rtok, const float* __restrict__ rw,
    const int* __restrict__ meta, __bf16* __restrict__ ACT) {
  // XCD-bijective remap: 3072 WGs = 8 XCDs x 384.
  const int orig = blockIdx.x;
  const int wgid = (orig & 7) * 384 + (orig >> 3);
  const int mx = wgid & 15;
  const int ny = (wgid >> 4) % 12;
  const int e  = wgid / 192;

  const int seg0 = meta[16 + e];
  const int cnt  = meta[16 + e + 1] - seg0;
  const int m0 = mx * 128;
  if (m0 >= cnt) return;
  const int n0 = ny * 64;

  __shared__ char As[16384];   // 128 rows x 128B, linear; src pre-swizzled
  __shared__ char Bs[16384];

  const int tid = threadIdx.x;
  const int l = tid & 63;
  const int w = tid >> 6;
  const int wm = w >> 1, wn = w & 1;
  const int swoff = 16 * ((l & 7) ^ (l >> 3));

  const char* baseA[4];
  const char* baseB[4];
#pragma unroll
  for (int q = 0; q < 4; ++q) {
    const int r = (w * 4 + q) * 8 + (l >> 3);
    int grow = m0 + r; if (grow >= cnt) grow = cnt - 1;
    const int tok = rtok[seg0 + grow];
    baseA[q] = (const char*)(XB + (size_t)tok * HID) + swoff;
    const int sec = r >> 6, s = r & 63;
    const int wrow = (s < 32) ? (n0 + sec * 32 + s) : (IMED + n0 + sec * 32 + (s - 32));
    baseB[q] = (const char*)(WguT + ((size_t)e * (2 * IMED) + wrow) * HID) + swoff;
  }

  f32x4 acc[4][4];   // ni 0,1 = gate ; 2,3 = up
  const f32x4 zero = {0.f, 0.f, 0.f, 0.f};
#pragma unroll
  for (int i = 0; i < 4; ++i)
#pragma unroll
    for (int j = 0; j < 4; ++j) acc[i][j] = zero;

  for (int k0b = 0; k0b < HID * 2; k0b += 128) {
#pragma unroll
    for (int q = 0; q < 4; ++q) {
      gload16(baseA[q] + k0b, &As[(w * 4 + q) * 1024]);
      gload16(baseB[q] + k0b, &Bs[(w * 4 + q) * 1024]);
    }
    __syncthreads();
#pragma unroll
    for (int ks = 0; ks < 2; ++ks) {
      const int colb = ks * 64 + (l >> 4) * 16;
      bf16x8 af[4], bf[4];
#pragma unroll
      for (int mi = 0; mi < 4; ++mi) {
        const int row = wm * 64 + mi * 16 + (l & 15);
        af[mi] = *(const bf16x8*)&As[row * 128 + (colb ^ ((row & 7) << 4))];
      }
#pragma unroll
      for (int ni = 0; ni < 4; ++ni) {
        const int row = wn * 64 + ni * 16 + (l & 15);
        bf[ni] = *(const bf16x8*)&Bs[row * 128 + (colb ^ ((row & 7) << 4))];
      }
#pragma unroll
      for (int mi = 0; mi < 4; ++mi)
#pragma unroll
        for (int ni = 0; ni < 4; ++ni)
          acc[mi][ni] = mfma16(af[mi], bf[ni], acc[mi][ni]);
    }
    __syncthreads();
  }

  const int cbase = n0 + wn * 32;
#pragma unroll
  for (int mi = 0; mi < 4; ++mi) {
    const int rb = wm * 64 + mi * 16 + ((l >> 4) << 2);
#pragma unroll
    for (int r = 0; r < 4; ++r) {
      const int row = m0 + rb + r;
      if (row < cnt) {
        const float wgt = rw[seg0 + row];
#pragma unroll
        for (int ni = 0; ni < 2; ++ni) {
          const float g = acc[mi][ni][r];
          const float u = acc[mi][ni + 2][r];
          const float s = g / (1.f + __expf(-g));
          ACT[(size_t)(seg0 + row) * IMED + cbase + ni * 16 + (l & 15)] = (__bf16)(s * u * wgt);
        }
      }
    }
  }
}

// ---------- GEMM2: 128 pairs x 128 H-cols, K=768, single-buffer, bf16 store ----------
__global__ __launch_bounds__(256) void moe_gemm2(
    const __bf16* __restrict__ ACT, const __bf16* __restrict__ WdT,
    const int* __restrict__ meta, __bf16* __restrict__ ACT2) {
  const int orig = blockIdx.x;               // 4096 WGs = 8 x 512
  const int wgid = (orig & 7) * 512 + (orig >> 3);
  const int mx = wgid & 15;
  const int ny = (wgid >> 4) & 15;
  const int e  = wgid >> 8;

  const int seg0 = meta[16 + e];
  const int cnt  = meta[16 + e + 1] - seg0;
  const int m0 = mx * 128;
  if (m0 >= cnt) return;
  const int n0 = ny * 128;

  __shared__ char As[16384];
  __shared__ char Bs[16384];

  const int tid = threadIdx.x;
  const int l = tid & 63;
  const int w = tid >> 6;
  const int wm = w >> 1, wn = w & 1;
  const int swoff = 16 * ((l & 7) ^ (l >> 3));

  const char* baseA[4];
  const char* baseB[4];
#pragma unroll
  for (int q = 0; q < 4; ++q) {
    const int r = (w * 4 + q) * 8 + (l >> 3);
    int grow = m0 + r; if (grow >= cnt) grow = cnt - 1;
    baseA[q] = (const char*)(ACT + (size_t)(seg0 + grow) * IMED) + swoff;
    baseB[q] = (const char*)(WdT + ((size_t)e * HID + n0 + r) * IMED) + swoff;
  }

  f32x4 acc[4][4];
  const f32x4 zero = {0.f, 0.f, 0.f, 0.f};
#pragma unroll
  for (int i = 0; i < 4; ++i)
#pragma unroll
    for (int j = 0; j < 4; ++j) acc[i][j] = zero;

  for (int k0b = 0; k0b < IMED * 2; k0b += 128) {
#pragma unroll
    for (int q = 0; q < 4; ++q) {
      gload16(baseA[q] + k0b, &As[(w * 4 + q) * 1024]);
      gload16(baseB[q] + k0b, &Bs[(w * 4 + q) * 1024]);
    }
    __syncthreads();
#pragma unroll
    for (int ks = 0; ks < 2; ++ks) {
      const int colb = ks * 64 + (l >> 4) * 16;
      bf16x8 af[4], bf[4];
#pragma unroll
      for (int mi = 0; mi < 4; ++mi) {
        const int row = wm * 64 + mi * 16 + (l & 15);
        af[mi] = *(const bf16x8*)&As[row * 128 + (colb ^ ((row & 7) << 4))];
      }
#pragma unroll
      for (int ni = 0; ni < 4; ++ni) {
        const int row = wn * 64 + ni * 16 + (l & 15);
        bf[ni] = *(const bf16x8*)&Bs[row * 128 + (colb ^ ((row & 7) << 4))];
      }
#pragma unroll
      for (int mi = 0; mi < 4; ++mi)
#pragma unroll
        for (int ni = 0; ni < 4; ++ni)
          acc[mi][ni] = mfma16(af[mi], bf[ni], acc[mi][ni]);
    }
    __syncthreads();
  }

#pragma unroll
  for (int mi = 0; mi < 4; ++mi) {
    const int rb = wm * 64 + mi * 16 + ((l >> 4) << 2);
#pragma unroll
    for (int r = 0; r < 4; ++r) {
      const int row = m0 + rb + r;
      if (row < cnt) {
#pragma unroll
        for (int ni = 0; ni < 4; ++ni)
          ACT2[(size_t)(seg0 + row) * HID + n0 + wn * 64 + ni * 16 + (l & 15)] =
              (__bf16)acc[mi][ni][r];
      }
    }
  }
}

// ---------- combine: out[t][h] = sum_k ACT2[ptok[t][k]][h] ----------
__global__ __launch_bounds__(256) void moe_combine(const __bf16* __restrict__ ACT2,
                                                   const int* __restrict__ ptok,
                                                   const int* __restrict__ pcnt,
                                                   float* __restrict__ out) {
  const int t = blockIdx.x;
  const int h = threadIdx.x * 8;
  const int n = pcnt[t];
  float a[8];
#pragma unroll
  for (int j = 0; j < 8; ++j) a[j] = 0.f;
  for (int k = 0; k < n; ++k) {
    const int p = ptok[t * TOPK + k];
    bf16x8 v = *(const bf16x8*)&ACT2[(size_t)p * HID + h];
#pragma unroll
    for (int j = 0; j < 8; ++j) a[j] += (float)v[j];
  }
  float4 o0 = {a[0], a[1], a[2], a[3]};
  float4 o1 = {a[4], a[5], a[6], a[7]};
  *(float4*)&out[(size_t)t * HID + h] = o0;
  *(float4*)&out[(size_t)t * HID + h + 4] = o1;
}

extern "C" void kernel_launch(void* const* d_in, const int* in_sizes, int n_in,
                              void* d_out, int out_size, void* d_ws, size_t ws_size,
                              hipStream_t stream) {
  const float* X   = (const float*)d_in[0];
  const float* GUP = (const float*)d_in[1];
  const float* DP  = (const float*)d_in[2];
  const int*   IDX = (const int*)d_in[3];
  const float* W   = (const float*)d_in[4];
  float* out = (float*)d_out;

  size_t off = 0;
  auto alloc = [&](size_t bytes) -> void* {
    void* p = (char*)d_ws + off;
    off = (off + bytes + 255) & ~(size_t)255;
    return p;
  };
  __bf16* XB      = (__bf16*)alloc((size_t)T_TOK * HID * 2);
  __bf16* WguT    = (__bf16*)alloc((size_t)NEXP * 2 * IMED * HID * 2);
  __bf16* WdT     = (__bf16*)alloc((size_t)NEXP * HID * IMED * 2);
  __bf16* ACT     = (__bf16*)alloc((size_t)(MAXPAIR + 128) * IMED * 2);
  float*  combine = (float*)alloc((size_t)T_TOK * NEXP * 4);
  int*    meta    = (int*)alloc(64 * 4);
  int*    rtok    = (int*)alloc((size_t)MAXPAIR * 4);
  float*  rw      = (float*)alloc((size_t)MAXPAIR * 4);
  int*    ptok    = (int*)alloc((size_t)T_TOK * TOPK * 4);
  int*    pcnt    = (int*)alloc((size_t)T_TOK * 4);
  if (off > ws_size) return;

  // ACT2 aliases WguT: GEMM1 (last reader of WguT) completes before GEMM2
  // (first writer of ACT2) on the same stream. 67.1 MB <= 100.7 MB region.
  __bf16* ACT2 = WguT;

  hipMemsetAsync(meta, 0, 256, stream);
  moe_cvt_x<<<T_TOK * HID / (256 * 8), 256, 0, stream>>>(X, XB);
  moe_transpose<<<dim3((2 * IMED) / 64, HID / 64, NEXP), 256, 0, stream>>>(GUP, WguT, HID, 2 * IMED);
  moe_transpose<<<dim3(HID / 64, IMED / 64, NEXP), 256, 0, stream>>>(DP, WdT, IMED, HID);
  moe_route_build<<<T_TOK / 256, 256, 0, stream>>>(IDX, W, combine, meta);
  moe_scan<<<1, 64, 0, stream>>>(meta);
  moe_scatter<<<T_TOK / 256, 256, 0, stream>>>(combine, meta, rtok, rw, ptok, pcnt);
  moe_gemm1<<<3072, 256, 0, stream>>>(XB, WguT, rtok, rw, meta, ACT);
  moe_gemm2<<<4096, 256, 0, stream>>>(ACT, WdT, meta, ACT2);
  moe_combine<<<T_TOK, 256, 0, stream>>>(ACT2, ptok, pcnt, out);
}